// Round 11
// baseline (1176.696 us; speedup 1.0000x reference)
//
#include <hip/hip_runtime.h>
#include <hip/hip_cooperative_groups.h>

namespace cg = cooperative_groups;

// 22-qubit, 3-layer RY variational circuit. Real/imag planes evolve
// independently (all gates real). Inputs bf16 (device-detected, f32 fallback
// preserves R6 semantics). Output: interleaved (re,im) bf16.
//
// R11: ONE cooperative persistent kernel (512 blocks x 512 threads, 2
// blocks/CU), 6 phases separated by grid.sync(). High passes use 8-lo tiles
// (8 waves, 64KB LDS in two 32KB e-pair regions -> 2 barriers, overlapped
// across 2 blocks/CU). Butterfly op assignment identical to R10 ->
// bit-identical output. Fallback: proven R10 7-kernel path.

#define NQ 22
#define NSTATES (1u << NQ)
#define IDXMASK (NSTATES - 1u)

__device__ __forceinline__ unsigned short f2bf(float x) {
  unsigned int b = __float_as_uint(x);
  b += 0x7FFFu + ((b >> 16) & 1u);   // round-to-nearest-even
  return (unsigned short)(b >> 16);
}
__device__ __forceinline__ float bf2f(unsigned short h) {
  return __uint_as_float((unsigned int)h << 16);
}

template <int BIT>
__device__ __forceinline__ void bf_regs(float (&v)[32], float c, float s) {
#pragma unroll
  for (int i = 0; i < 32; ++i) {
    if (!(i & BIT)) {
      float x0 = v[i], x1 = v[i | BIT];
      v[i]       = c * x0 - s * x1;
      v[i | BIT] = s * x0 + c * x1;
    }
  }
}
template <int LMASK>
__device__ __forceinline__ void bf_shfl(float (&v)[32], float c, float s, int lane) {
  float sg = (lane & LMASK) ? s : -s;
#pragma unroll
  for (int i = 0; i < 32; ++i) {
    float p = __shfl_xor(v[i], LMASK, 64);
    v[i] = fmaf(sg, p, c * v[i]);
  }
}

// ---------------- persistent-kernel helpers ----------------

// per-phase params: decode 11 angles, sincos into register arrays.
__device__ __forceinline__ void load_cs(const void* prm, int f, int base,
                                        float (&C)[11], float (&S)[11]) {
#pragma unroll
  for (int k = 0; k < 11; ++k) {
    float a = f ? bf2f(((const unsigned short*)prm)[base + k])
                : ((const float*)prm)[base + k];
    float sv, cv;
    sincosf(0.5f * a, &sv, &cv);
    C[k] = cv; S[k] = sv;
  }
}

// Low-pass butterflies q0..q10 + per-wave A->B exchange (stride-32 rotation
// swizzle, wave-local -> no barrier). exw = 2048-f32 slice.
__device__ __forceinline__ void low_butterflies(float (&v)[32], float* exw,
                                                const float (&C)[11],
                                                const float (&S)[11], int lane) {
  bf_regs<1>(v, C[0], S[0]);
  bf_regs<2>(v, C[1], S[1]);
  bf_regs<4>(v, C[8], S[8]);
  bf_regs<8>(v, C[9], S[9]);
  bf_regs<16>(v, C[10], S[10]);
  bf_shfl<1>(v, C[2], S[2], lane);
  bf_shfl<2>(v, C[3], S[3], lane);
  bf_shfl<4>(v, C[4], S[4], lane);
#pragma unroll
  for (int i = 0; i < 32; ++i) exw[lane * 32 + ((i + lane) & 31)] = v[i];
#pragma unroll
  for (int rp = 0; rp < 8; ++rp) {
    int row = (rp << 3) | (lane & 7);
    int col = (lane >> 3) << 2;
#pragma unroll
    for (int e = 0; e < 4; ++e)
      v[rp * 4 + e] = exw[row * 32 + ((col + e + row) & 31)];
  }
  bf_regs<4>(v, C[5], S[5]);
  bf_regs<8>(v, C[6], S[6]);
  bf_regs<16>(v, C[7], S[7]);
}

__device__ __forceinline__ void low_store16(float (&v)[32], unsigned short* dst,
                                            int base, int lane) {
#pragma unroll
  for (int rp = 0; rp < 8; ++rp) {
    ushort4 t = make_ushort4(f2bf(v[rp*4+0]), f2bf(v[rp*4+1]),
                             f2bf(v[rp*4+2]), f2bf(v[rp*4+3]));
    *reinterpret_cast<ushort4*>(dst + base + ((lane & 7) << 2) + (rp << 5) +
                                ((lane >> 3) << 8)) = t;
  }
}

// High-pass exchange addressing within a 8192-f32 region (epar added at bit0).
// bank bits: epar, qp, hi0^hi8, hi1^hi9, hi3 — lane-varying on both sides.
__device__ __forceinline__ int haddr(int hi, int qp) {
  return (qp << 1) | (((hi ^ (hi >> 8)) & 1) << 2) |
         ((((hi >> 1) ^ (hi >> 9)) & 1) << 3) | (((hi >> 3) & 1) << 4) |
         (((hi >> 2) & 1) << 5) | (((hi >> 4) & 15) << 6) |
         (((hi >> 8) & 7) << 10);
}

__device__ __forceinline__ void high_load16(float (&v)[32],
                                            const unsigned short* buf,
                                            int hiA0, int L0, int qp) {
#pragma unroll
  for (int r = 0; r < 8; ++r) {
    int hi = hiA0 | (r << 8);
    ushort4 t = *reinterpret_cast<const ushort4*>(buf + hi * 2048 + L0 + (qp << 2));
    v[r*4+0]=bf2f(t.x); v[r*4+1]=bf2f(t.y); v[r*4+2]=bf2f(t.z); v[r*4+3]=bf2f(t.w);
  }
}

// High butterflies q11..q21. A: hi = lane[4:1]->hi[3:0], lane5->hi4,
// wid->hi[7:5], r->hi[10:8].  B: wid->hi[2:0], lane5->hi3, rp->hi[6:4],
// lane1->hi7, lane[4:2]->hi[10:8]. Op assignment per qubit == R10.
__device__ __forceinline__ void high_core(float (&v)[32], float (&nv)[32],
                                          float* ex, const float (&C)[11],
                                          const float (&S)[11], int lane,
                                          int hiA0, int hiB0, int qp) {
  bf_regs<4>(v, C[8], S[8]);        // q19
  bf_regs<8>(v, C[9], S[9]);        // q20
  bf_regs<16>(v, C[10], S[10]);     // q21
  bf_shfl<2>(v, C[0], S[0], lane);     // q11 (hi0 = lane1)
  bf_shfl<4>(v, C[1], S[1], lane);     // q12
  bf_shfl<8>(v, C[2], S[2], lane);     // q13
  bf_shfl<16>(v, C[3], S[3], lane);    // q14 (hi3 = lane4)
#pragma unroll
  for (int rnd = 0; rnd < 2; ++rnd) {
    float* reg = ex + rnd * 8192;
#pragma unroll
    for (int r = 0; r < 8; ++r) {
      int hi = hiA0 | (r << 8);
      *reinterpret_cast<float2*>(reg + haddr(hi, qp)) =
          make_float2(v[r*4 + rnd*2 + 0], v[r*4 + rnd*2 + 1]);
    }
    __syncthreads();
#pragma unroll
    for (int rp = 0; rp < 8; ++rp) {
      int hi = hiB0 | (rp << 4);
      float2 t = *reinterpret_cast<const float2*>(reg + haddr(hi, qp));
      nv[rp*4 + rnd*2 + 0] = t.x;
      nv[rp*4 + rnd*2 + 1] = t.y;
    }
  }
  bf_regs<4>(nv, C[4], S[4]);       // q15 (hi4 = rp bit0)
  bf_regs<8>(nv, C[5], S[5]);       // q16
  bf_regs<16>(nv, C[6], S[6]);      // q17
  bf_shfl<2>(nv, C[7], S[7], lane);    // q18 (hi7 = lane1)
}

// ---------------- the persistent cooperative kernel ----------------
__global__ void __launch_bounds__(512, 4)
kcirc(const void* re, const void* im, const void* prm,
      unsigned short* W0r, unsigned short* W0i,
      unsigned short* W1r, unsigned short* W1i,
      unsigned int* out32) {
  __shared__ float ex[16384];   // 64KB: low = 8 x 2048 wave slices; high = 2 x 8192
  cg::grid_group grid = cg::this_grid();
  int tid = threadIdx.x, lane = tid & 63, wid = tid >> 6;
  int blk = blockIdx.x;

  // input dtype flag: uniform probe (f32 low-halves are mantissa junk)
  int f;
  {
    const unsigned int* p = (const unsigned int*)re;
    int bad = 0;
#pragma unroll
    for (int i = 0; i < 64; ++i) bad |= (((p[i] >> 7) & 0xFFu) >= 0x90u);
    f = bad ? 0 : 1;
  }

  float C[11], S[11];
  float v[32], nv[32];
  float* exw = ex + wid * 2048;
  int g = blk * 8 + wid;                 // low-phase wave-chunk id [0,4096)
  int lpl = g >> 11;
  int lbase = (g & 2047) << 11;
  int qp = lane & 1;
  int hiA0 = ((lane >> 1) & 15) | (((lane >> 5) & 1) << 4) | (wid << 5);
  int hiB0 = wid | (((lane >> 5) & 1) << 3) | (((lane >> 1) & 1) << 7) |
             (((lane >> 2) & 7) << 8);
  int hpl = blk & 1;                     // high-phase plane
  int hL0 = (blk >> 1) << 3;             // high-phase lo-tile base

  // ---- P1: layer0 low, inputs -> W0 ----
  load_cs(prm, f, 0, C, S);
  {
    const void* src = (lpl ^ (f ? 0 : 1)) ? im : re;
    unsigned short* dst = lpl ? W0i : W0r;
    if (f) {
      const ushort4* sp = (const ushort4*)src;
#pragma unroll
      for (int r = 0; r < 8; ++r) {
        ushort4 t = sp[(lbase + (r << 8) + (lane << 2)) >> 2];
        v[r*4+0]=bf2f(t.x); v[r*4+1]=bf2f(t.y); v[r*4+2]=bf2f(t.z); v[r*4+3]=bf2f(t.w);
      }
    } else {
      const float* sp = (const float*)src;
#pragma unroll
      for (int r = 0; r < 8; ++r) {
        float4 t = *reinterpret_cast<const float4*>(sp + lbase + (r << 8) + (lane << 2));
        v[r*4+0]=t.x; v[r*4+1]=t.y; v[r*4+2]=t.z; v[r*4+3]=t.w;
      }
    }
    low_butterflies(v, exw, C, S, lane);
    low_store16(v, dst, lbase, lane);
  }
  __threadfence(); grid.sync();

  // ---- P2: layer0 high, W0 in-place ----
  load_cs(prm, f, 11, C, S);
  {
    unsigned short* buf = hpl ? W0i : W0r;
    high_load16(v, buf, hiA0, hL0, qp);
    high_core(v, nv, ex, C, S, lane, hiA0, hiB0, qp);
#pragma unroll
    for (int rp = 0; rp < 8; ++rp) {
      int hi = hiB0 | (rp << 4);
      ushort4 t = make_ushort4(f2bf(nv[rp*4+0]), f2bf(nv[rp*4+1]),
                               f2bf(nv[rp*4+2]), f2bf(nv[rp*4+3]));
      *reinterpret_cast<ushort4*>(buf + hi * 2048 + hL0 + (qp << 2)) = t;
    }
  }
  __threadfence(); grid.sync();

  // ---- P3: layer1 low, W0 --sigma-gather--> W1 ----
  load_cs(prm, f, 22, C, S);
  {
    const unsigned short* src = lpl ? W0i : W0r;
    unsigned short* dst = lpl ? W1i : W1r;
#pragma unroll
    for (int r = 0; r < 8; ++r) {
      unsigned X = lbase + (r << 8) + (lane << 2);
      unsigned sX = (X ^ (X << 1)) & IDXMASK;
      uint4 U = *reinterpret_cast<const uint4*>(src + (sX & ~7u));
      bool h = (sX & 4u) != 0;
      unsigned a0 = h ? U.z : U.x;
      unsigned a1 = h ? U.w : U.y;
      unsigned a2 = h ? U.y : U.w;
      unsigned a3 = h ? U.x : U.z;
      v[r*4+0] = bf2f((unsigned short)(a0 & 0xFFFFu));
      v[r*4+1] = bf2f((unsigned short)(a1 >> 16));
      v[r*4+2] = bf2f((unsigned short)(a2 & 0xFFFFu));
      v[r*4+3] = bf2f((unsigned short)(a3 >> 16));
    }
    low_butterflies(v, exw, C, S, lane);
    low_store16(v, dst, lbase, lane);
  }
  __threadfence(); grid.sync();

  // ---- P4: layer1 high, W1 in-place ----
  load_cs(prm, f, 33, C, S);
  {
    unsigned short* buf = hpl ? W1i : W1r;
    high_load16(v, buf, hiA0, hL0, qp);
    high_core(v, nv, ex, C, S, lane, hiA0, hiB0, qp);
#pragma unroll
    for (int rp = 0; rp < 8; ++rp) {
      int hi = hiB0 | (rp << 4);
      ushort4 t = make_ushort4(f2bf(nv[rp*4+0]), f2bf(nv[rp*4+1]),
                               f2bf(nv[rp*4+2]), f2bf(nv[rp*4+3]));
      *reinterpret_cast<ushort4*>(buf + hi * 2048 + hL0 + (qp << 2)) = t;
    }
  }
  __threadfence(); grid.sync();

  // ---- P5: layer2 low, W1 --sigma-gather--> W0 ----
  load_cs(prm, f, 44, C, S);
  {
    const unsigned short* src = lpl ? W1i : W1r;
    unsigned short* dst = lpl ? W0i : W0r;
#pragma unroll
    for (int r = 0; r < 8; ++r) {
      unsigned X = lbase + (r << 8) + (lane << 2);
      unsigned sX = (X ^ (X << 1)) & IDXMASK;
      uint4 U = *reinterpret_cast<const uint4*>(src + (sX & ~7u));
      bool h = (sX & 4u) != 0;
      unsigned a0 = h ? U.z : U.x;
      unsigned a1 = h ? U.w : U.y;
      unsigned a2 = h ? U.y : U.w;
      unsigned a3 = h ? U.x : U.z;
      v[r*4+0] = bf2f((unsigned short)(a0 & 0xFFFFu));
      v[r*4+1] = bf2f((unsigned short)(a1 >> 16));
      v[r*4+2] = bf2f((unsigned short)(a2 & 0xFFFFu));
      v[r*4+3] = bf2f((unsigned short)(a3 >> 16));
    }
    low_butterflies(v, exw, C, S, lane);
    low_store16(v, dst, lbase, lane);
  }
  __threadfence(); grid.sync();

  // ---- P6: layer2 high, W0 (both planes) -> packed bf16 out ----
  if (blk < 256) {
    load_cs(prm, f, 55, C, S);
    int L0 = blk << 3;
    unsigned pk[16];
    // plane re
    high_load16(v, W0r, hiA0, L0, qp);
    high_core(v, nv, ex, C, S, lane, hiA0, hiB0, qp);
#pragma unroll
    for (int k = 0; k < 16; ++k)
      pk[k] = (unsigned)f2bf(nv[2*k]) | ((unsigned)f2bf(nv[2*k+1]) << 16);
    // plane im (region hazards covered by high_core's internal barriers)
    high_load16(v, W0i, hiA0, L0, qp);
    high_core(v, nv, ex, C, S, lane, hiA0, hiB0, qp);
#pragma unroll
    for (int rp = 0; rp < 8; ++rp) {
      int hi = hiB0 | (rp << 4);
      unsigned idx = (unsigned)hi * 2048u + L0 + (qp << 2);
      int i0 = rp * 4;
      uint4 t;
      t.x = (pk[i0>>1] & 0xFFFFu)     | ((unsigned)f2bf(nv[i0+0]) << 16);
      t.y = (pk[i0>>1] >> 16)         | ((unsigned)f2bf(nv[i0+1]) << 16);
      t.z = (pk[(i0+2)>>1] & 0xFFFFu) | ((unsigned)f2bf(nv[i0+2]) << 16);
      t.w = (pk[(i0+2)>>1] >> 16)     | ((unsigned)f2bf(nv[i0+3]) << 16);
      *reinterpret_cast<uint4*>(out32 + idx) = t;
    }
  }
}

// ================= R10 fallback path (proven, unchanged) =================
__global__ void ksetup(const unsigned int* __restrict__ probe,
                       const void* __restrict__ prm,
                       float* __restrict__ csb, int* __restrict__ flagp) {
  __shared__ int anybad;
  if (threadIdx.x == 0) anybad = 0;
  __syncthreads();
  int bad = 0;
  for (int i = threadIdx.x; i < 4096; i += 256) {
    unsigned e = (probe[i] >> 7) & 0xFFu;
    bad |= (e >= 0x90u);
  }
  if (bad) anybad = 1;
  __syncthreads();
  int f = anybad ? 0 : 1;
  if (threadIdx.x == 0) *flagp = f;
  int i = threadIdx.x;
  if (i < 66) {
    float a = f ? bf2f(((const unsigned short*)prm)[i]) : ((const float*)prm)[i];
    float sv, cv;
    sincosf(0.5f * a, &sv, &cv);
    csb[i] = cv; csb[66 + i] = sv;
  }
}

__device__ __forceinline__ void low_body_f(float (&v)[32], float* exl,
                                           const float* C, const float* S, int lane) {
  bf_regs<1>(v, C[0], S[0]);
  bf_regs<2>(v, C[1], S[1]);
  bf_regs<4>(v, C[8], S[8]);
  bf_regs<8>(v, C[9], S[9]);
  bf_regs<16>(v, C[10], S[10]);
  bf_shfl<1>(v, C[2], S[2], lane);
  bf_shfl<2>(v, C[3], S[3], lane);
  bf_shfl<4>(v, C[4], S[4], lane);
#pragma unroll
  for (int i = 0; i < 32; ++i) exl[lane * 33 + i] = v[i];
#pragma unroll
  for (int rp = 0; rp < 8; ++rp) {
    int row = (rp << 3) | (lane & 7);
    int col = (lane >> 3) << 2;
#pragma unroll
    for (int e = 0; e < 4; ++e) v[rp * 4 + e] = exl[row * 33 + col + e];
  }
  bf_regs<4>(v, C[5], S[5]);
  bf_regs<8>(v, C[6], S[6]);
  bf_regs<16>(v, C[7], S[7]);
}

__device__ __forceinline__ void low_store_f(float (&v)[32], unsigned short* dst,
                                            int base, int lane) {
#pragma unroll
  for (int rp = 0; rp < 8; ++rp) {
    ushort4 t = make_ushort4(f2bf(v[rp*4+0]), f2bf(v[rp*4+1]),
                             f2bf(v[rp*4+2]), f2bf(v[rp*4+3]));
    *reinterpret_cast<ushort4*>(dst + base + ((lane & 7) << 2) + (rp << 5) +
                                ((lane >> 3) << 8)) = t;
  }
}

__global__ void __launch_bounds__(256)
klow_in(const void* s0, const void* s1, unsigned short* d0, unsigned short* d1,
        const float* __restrict__ csb, const int* __restrict__ flag) {
  __shared__ float exs[4][64 * 33];
  int tid = threadIdx.x, pl = blockIdx.y;
  int f = *flag;
  const void* src = (pl ^ (f ? 0 : 1)) ? s1 : s0;
  unsigned short* dst = pl ? d1 : d0;
  int lane = tid & 63, wd = tid >> 6;
  int base = (blockIdx.x * 4 + wd) << 11;
  const float* C = csb;
  const float* S = csb + 66;
  float v[32];
  if (f) {
    const ushort4* sp = (const ushort4*)src;
#pragma unroll
    for (int r = 0; r < 8; ++r) {
      ushort4 t = sp[(base + (r << 8) + (lane << 2)) >> 2];
      v[r*4+0]=bf2f(t.x); v[r*4+1]=bf2f(t.y); v[r*4+2]=bf2f(t.z); v[r*4+3]=bf2f(t.w);
    }
  } else {
    const float* sp = (const float*)src;
#pragma unroll
    for (int r = 0; r < 8; ++r) {
      float4 t = *reinterpret_cast<const float4*>(sp + base + (r << 8) + (lane << 2));
      v[r*4+0]=t.x; v[r*4+1]=t.y; v[r*4+2]=t.z; v[r*4+3]=t.w;
    }
  }
  low_body_f(v, exs[wd], C, S, lane);
  low_store_f(v, dst, base, lane);
}

__global__ void __launch_bounds__(256)
klow_g(const unsigned short* s0, const unsigned short* s1,
       unsigned short* d0, unsigned short* d1,
       const float* __restrict__ csb, int L) {
  __shared__ float exs[4][64 * 33];
  int tid = threadIdx.x, pl = blockIdx.y;
  const unsigned short* src = pl ? s1 : s0;
  unsigned short* dst = pl ? d1 : d0;
  int lane = tid & 63, wd = tid >> 6;
  int base = (blockIdx.x * 4 + wd) << 11;
  const float* C = csb + L * 22;
  const float* S = csb + 66 + L * 22;
  float v[32];
#pragma unroll
  for (int r = 0; r < 8; ++r) {
    unsigned X = base + (r << 8) + (lane << 2);
    unsigned sX = (X ^ (X << 1)) & IDXMASK;
    uint4 U = *reinterpret_cast<const uint4*>(src + (sX & ~7u));
    bool h = (sX & 4u) != 0;
    unsigned a0 = h ? U.z : U.x;
    unsigned a1 = h ? U.w : U.y;
    unsigned a2 = h ? U.y : U.w;
    unsigned a3 = h ? U.x : U.z;
    v[r*4+0] = bf2f((unsigned short)(a0 & 0xFFFFu));
    v[r*4+1] = bf2f((unsigned short)(a1 >> 16));
    v[r*4+2] = bf2f((unsigned short)(a2 & 0xFFFFu));
    v[r*4+3] = bf2f((unsigned short)(a3 >> 16));
  }
  low_body_f(v, exs[wd], C, S, lane);
  low_store_f(v, dst, base, lane);
}

__device__ __forceinline__ int exaddr_f(int hi, int qq) {
  return (qq << 1) | (((hi ^ (hi >> 7)) & 1) << 3) |
         (((hi >> 1) & 7) << 4) | (((hi >> 4) & 15) << 7) |
         (((hi >> 8) & 7) << 11);
}

__device__ __forceinline__ void high_core_f(float (&v)[32], float (&nv)[32],
                                            float* ex, const float* C,
                                            const float* S, int lane, int hiA,
                                            int hiB, int qq) {
  bf_regs<4>(v, C[8], S[8]);
  bf_regs<8>(v, C[9], S[9]);
  bf_regs<16>(v, C[10], S[10]);
  bf_shfl<4>(v, C[0], S[0], lane);
  bf_shfl<8>(v, C[1], S[1], lane);
  bf_shfl<16>(v, C[2], S[2], lane);
  bf_shfl<32>(v, C[3], S[3], lane);
#pragma unroll
  for (int eh = 0; eh < 2; ++eh) {
    if (eh) __syncthreads();
#pragma unroll
    for (int r = 0; r < 8; ++r) {
      int hi = hiA | (r << 8);
      *reinterpret_cast<float2*>(ex + exaddr_f(hi, qq)) =
          make_float2(v[r*4 + eh*2 + 0], v[r*4 + eh*2 + 1]);
    }
    __syncthreads();
#pragma unroll
    for (int rp = 0; rp < 8; ++rp) {
      int hi = hiB | (rp << 4);
      float2 t = *reinterpret_cast<const float2*>(ex + exaddr_f(hi, qq));
      nv[rp*4 + eh*2 + 0] = t.x;
      nv[rp*4 + eh*2 + 1] = t.y;
    }
  }
  bf_regs<4>(nv, C[4], S[4]);
  bf_regs<8>(nv, C[5], S[5]);
  bf_regs<16>(nv, C[6], S[6]);
  bf_shfl<4>(nv, C[7], S[7], lane);
}

__device__ __forceinline__ void high_load_f(float (&v)[32], const unsigned short* buf,
                                            int hiA, int L0, int qq) {
#pragma unroll
  for (int r = 0; r < 8; ++r) {
    int hi = hiA | (r << 8);
    ushort4 t = *reinterpret_cast<const ushort4*>(buf + hi * 2048 + L0 + (qq << 2));
    v[r*4+0]=bf2f(t.x); v[r*4+1]=bf2f(t.y); v[r*4+2]=bf2f(t.z); v[r*4+3]=bf2f(t.w);
  }
}

__global__ void __launch_bounds__(1024)
khigh_ip(unsigned short* b0, unsigned short* b1, const float* __restrict__ csb,
         int L) {
  __shared__ float ex[16384];
  int tid = threadIdx.x, pl = blockIdx.y;
  unsigned short* buf = pl ? b1 : b0;
  const float* C = csb + L * 22 + 11;
  const float* S = csb + 66 + L * 22 + 11;
  int lane = tid & 63, w = tid >> 6;
  int L0 = blockIdx.x << 4;
  int qq = lane & 3;
  int hiA = ((lane >> 2) & 15) | (w << 4);
  int hiB = w | (((lane >> 2) & 1) << 7) | ((lane >> 3) << 8);
  float v[32], nv[32];
  high_load_f(v, buf, hiA, L0, qq);
  high_core_f(v, nv, ex, C, S, lane, hiA, hiB, qq);
#pragma unroll
  for (int rp = 0; rp < 8; ++rp) {
    int hi = hiB | (rp << 4);
    ushort4 t = make_ushort4(f2bf(nv[rp*4+0]), f2bf(nv[rp*4+1]),
                             f2bf(nv[rp*4+2]), f2bf(nv[rp*4+3]));
    *reinterpret_cast<ushort4*>(buf + hi * 2048 + L0 + ((lane & 3) << 2)) = t;
  }
}

__global__ void __launch_bounds__(1024)
khigh_out(const unsigned short* b0, const unsigned short* b1,
          const float* __restrict__ csb, unsigned int* __restrict__ out32) {
  __shared__ float ex[16384];
  int tid = threadIdx.x;
  const float* C = csb + 2 * 22 + 11;
  const float* S = csb + 66 + 2 * 22 + 11;
  int lane = tid & 63, w = tid >> 6;
  int L0 = blockIdx.x << 4;
  int qq = lane & 3;
  int hiA = ((lane >> 2) & 15) | (w << 4);
  int hiB = w | (((lane >> 2) & 1) << 7) | ((lane >> 3) << 8);
  float v[32], nv[32];
  unsigned pk[16];
  high_load_f(v, b0, hiA, L0, qq);
  high_core_f(v, nv, ex, C, S, lane, hiA, hiB, qq);
#pragma unroll
  for (int k = 0; k < 16; ++k)
    pk[k] = (unsigned)f2bf(nv[2*k]) | ((unsigned)f2bf(nv[2*k+1]) << 16);
  __syncthreads();
  high_load_f(v, b1, hiA, L0, qq);
  high_core_f(v, nv, ex, C, S, lane, hiA, hiB, qq);
#pragma unroll
  for (int rp = 0; rp < 8; ++rp) {
    int hi = hiB | (rp << 4);
    unsigned idx = (unsigned)hi * 2048u + L0 + ((lane & 3) << 2);
    int i0 = rp * 4;
    uint4 t;
    t.x = (pk[i0>>1] & 0xFFFFu)     | ((unsigned)f2bf(nv[i0+0]) << 16);
    t.y = (pk[i0>>1] >> 16)         | ((unsigned)f2bf(nv[i0+1]) << 16);
    t.z = (pk[(i0+2)>>1] & 0xFFFFu) | ((unsigned)f2bf(nv[i0+2]) << 16);
    t.w = (pk[(i0+2)>>1] >> 16)     | ((unsigned)f2bf(nv[i0+3]) << 16);
    *reinterpret_cast<uint4*>(out32 + idx) = t;
  }
}

// ---------------- tier-C fallback (proven R6) ----------------
__global__ void __launch_bounds__(256)
kinit(const void* s0, const void* s1, float* d0, float* d1,
      const int* __restrict__ flag, int basepl) {
  int pl = blockIdx.y + basepl;
  int f = *flag;
  const void* src = (pl ^ (f ? 0 : 1)) ? s1 : s0;
  float* dst = pl ? d1 : d0;
  unsigned p = blockIdx.x * 256 + threadIdx.x;
  unsigned q = (p ^ (p << 2)) & IDXMASK;
  dst[p] = f ? bf2f(((const unsigned short*)src)[q]) : ((const float*)src)[q];
}
__global__ void __launch_bounds__(256)
kpass(float* b0, float* b1, const float* __restrict__ csb,
      int L, int qa, unsigned ma, unsigned mb) {
  int k = L * 22 + qa;
  float ca = csb[k], sa = csb[66 + k];
  float cb = csb[k + 1], sb = csb[66 + k + 1];
  float* buf = blockIdx.y ? b1 : b0;
  unsigned t = blockIdx.x * 256 + threadIdx.x;
  unsigned j = (t & ((1u << qa) - 1u)) | ((t >> qa) << (qa + 2));
  unsigned p = j;
  if (L == 0)      { p ^= p << 2; p ^= p << 4; p ^= p << 8; p ^= p << 16; }
  else if (L == 1) { p ^= p << 1; p ^= p << 2; p ^= p << 4; p ^= p << 8; p ^= p << 16; }
  p &= IDXMASK;
  unsigned mc = ma ^ mb;
  float x0 = buf[p], x1 = buf[p ^ ma], x2 = buf[p ^ mb], x3 = buf[p ^ mc];
  float y0 = ca * x0 - sa * x1, y1 = sa * x0 + ca * x1;
  float y2 = ca * x2 - sa * x3, y3 = sa * x2 + ca * x3;
  buf[p]      = cb * y0 - sb * y2;
  buf[p ^ ma] = cb * y1 - sb * y3;
  buf[p ^ mb] = sb * y0 + cb * y2;
  buf[p ^ mc] = sb * y1 + cb * y3;
}
__global__ void __launch_bounds__(256)
kpark(const float* __restrict__ fv, unsigned short* __restrict__ park) {
  unsigned j = blockIdx.x * 256 + threadIdx.x;
  park[j] = f2bf(fv[j]);
}
__global__ void __launch_bounds__(256)
kmerge(const unsigned short* __restrict__ park, unsigned int* outw) {
  unsigned j = blockIdx.x * 256 + threadIdx.x;
  float vv = __uint_as_float(outw[j]);
  outw[j] = (unsigned)park[j] | ((unsigned)f2bf(vv) << 16);
}
static inline unsigned pmask(int q, int L) {
  unsigned r = 0;
  if (L == 0)      for (unsigned m = 1u << q; m < NSTATES; m <<= 2) r ^= m;
  else if (L == 1) for (unsigned m = 1u << q; m < NSTATES; m <<= 1) r ^= m;
  else r = 1u << q;
  return r;
}

extern "C" void kernel_launch(void* const* d_in, const int* in_sizes, int n_in,
                              void* d_out, int out_size, void* d_ws, size_t ws_size,
                              hipStream_t stream) {
  (void)out_size;
  const void* prm = d_in[0];
  const void* re  = d_in[1];
  const void* im  = d_in[2];
  if (in_sizes[0] != 66) {   // defensive size-based remap
    const void* big[2] = {nullptr, nullptr};
    int nb = 0;
    for (int i = 0; i < n_in; ++i) {
      if (in_sizes[i] == 66) prm = d_in[i];
      else if (nb < 2) big[nb++] = d_in[i];
    }
    if (nb == 2) { re = big[0]; im = big[1]; }
  }
  dim3 blk(256);

  if (ws_size >= (size_t)NSTATES * 8 + 1024) {
    unsigned short* W0r = (unsigned short*)d_ws;
    unsigned short* W0i = W0r + NSTATES;
    unsigned short* W1r = W0i + NSTATES;
    unsigned short* W1i = W1r + NSTATES;
    float* csb = (float*)(W1i + NSTATES);
    int* flag = (int*)(csb + 140);
    unsigned int* outp = (unsigned int*)d_out;

    // ---- try the single cooperative persistent kernel ----
    {
      const void* rep = re; const void* imp = im; const void* prmp = prm;
      unsigned short* a0 = W0r; unsigned short* a1 = W0i;
      unsigned short* a2 = W1r; unsigned short* a3 = W1i;
      unsigned int* op = outp;
      void* args[] = {(void*)&rep, (void*)&imp, (void*)&prmp,
                      (void*)&a0, (void*)&a1, (void*)&a2, (void*)&a3,
                      (void*)&op};
      hipError_t cerr = hipLaunchCooperativeKernel((const void*)kcirc,
                          dim3(512), dim3(512), args, 0, stream);
      if (cerr == hipSuccess) return;
      (void)hipGetLastError();   // clear, fall back to multi-kernel path
    }

    // ---- fallback: proven R10 7-kernel pipeline ----
    ksetup<<<1, 256, 0, stream>>>((const unsigned int*)re, prm, csb, flag);
    dim3 gl(512, 2), gh(128, 2);
    klow_in<<<gl, blk, 0, stream>>>(re, im, W0r, W0i, csb, flag);
    khigh_ip<<<gh, 1024, 0, stream>>>(W0r, W0i, csb, 0);
    klow_g<<<gl, blk, 0, stream>>>(W0r, W0i, W1r, W1i, csb, 1);
    khigh_ip<<<gh, 1024, 0, stream>>>(W1r, W1i, csb, 1);
    klow_g<<<gl, blk, 0, stream>>>(W1r, W1i, W0r, W0i, csb, 2);
    khigh_out<<<dim3(128, 1), 1024, 0, stream>>>(W0r, W0i, csb, outp);
  } else {
    // ---- tier C (proven): d_out as f32 buffer; ~8.4MB ws ----
    float* F = (float*)d_out;
    unsigned short* park = (unsigned short*)d_ws;
    float* csb = (float*)((char*)d_ws + (size_t)NSTATES * 2);
    int* flag = (int*)(csb + 140);
    ksetup<<<1, 256, 0, stream>>>((const unsigned int*)re, prm, csb, flag);
    kinit<<<dim3(16384, 1), blk, 0, stream>>>(re, im, F, F, flag, 0);
    for (int L = 0; L < 3; ++L)
      for (int qa = 0; qa < 22; qa += 2)
        kpass<<<dim3(4096, 1), blk, 0, stream>>>(F, F, csb, L, qa,
                                                 pmask(qa, L), pmask(qa + 1, L));
    kpark<<<dim3(16384), blk, 0, stream>>>(F, park);
    kinit<<<dim3(16384, 1), blk, 0, stream>>>(re, im, F, F, flag, 1);
    for (int L = 0; L < 3; ++L)
      for (int qa = 0; qa < 22; qa += 2)
        kpass<<<dim3(4096, 1), blk, 0, stream>>>(F, F, csb, L, qa,
                                                 pmask(qa, L), pmask(qa + 1, L));
    kmerge<<<dim3(16384), blk, 0, stream>>>(park, (unsigned int*)d_out);
  }
}

// Round 13
// 106.040 us; speedup vs baseline: 11.0967x; 11.0967x over previous
//
#include <hip/hip_runtime.h>

// 22-qubit, 3-layer RY variational circuit — forward-frame 2-sweep version.
// Real/imag planes evolve independently (all gates real).
//
// Forward frame: state kept in natural position order; CNOT chains folded into
// rotation masks/signs instead of moving data. sigma(x) = x ^ (x<<1).
//   L0 q: mask e_q,               sign = p_q
//   L1 q: mask sigma(e_q)=e_q^e_{q+1},  sign = parity(p_0..p_q)
//   L2 q: mask sigma^2(e_q)=e_q^e_{q+2}, sign = parity(p_q, p_{q-2}, ...)
//   output: out[l] = buf[sigma^2(l)]  (final gather, kfinal)
// All cross-sweep reorderings verified to commute (f1(m2)==f2(m1) mod 2).
//
// R13 FIX: rot<> pair enumeration for multi-bit reg-masks — iterate by the
// LOWEST set bit of MR (j = i ^ MR), not `!(i & MR)` (which skipped the
// 01<->10 pairs of two-bit masks; 19 gates were half-applied -> absmax 0.93).
//
// Pipeline: ksetup -> ksweep1 (masks bits0..13) -> ksweep2 (bits12..21)
// -> kfinal. W intermediates f32. Fallback: proven R6 tier-C.

#define NQ 22
#define NSTATES (1u << NQ)
#define IDXMASK (NSTATES - 1u)

__device__ __forceinline__ unsigned short f2bf(float x) {
  unsigned int b = __float_as_uint(x);
  b += 0x7FFFu + ((b >> 16) & 1u);   // round-to-nearest-even
  return (unsigned short)(b >> 16);
}
__device__ __forceinline__ float bf2f(unsigned short h) {
  return __uint_as_float((unsigned int)h << 16);
}
// LDS address swizzle (14-bit local index): bank bits 0..4 get l0..4^l5..9^l10..13
__device__ __forceinline__ unsigned SW(unsigned l) {
  return l ^ ((l >> 5) & 31u) ^ ((l >> 10) & 31u);
}

// Generic RY butterfly. Pairs differ by lane-mask ML (shfl) and/or reg-mask MR.
// SM = sign functional support in p-bits; RS = shift of reg idx into p-bits.
// Element with total parity 0: new = c*me - s*other; parity 1: +s.
template <int ML, int MR, int RS, unsigned SM>
__device__ __forceinline__ void rot(float (&v)[32], float c, float s, unsigned pbase) {
  int sb = __popc(pbase & SM) & 1;
  float sp = sb ? s : -s;   // coefficient for elements with reg-part parity 0
  constexpr int LB = MR & (-MR);   // lowest set bit (pair enumerator)
  if (ML == 0) {
#pragma unroll
    for (int i = 0; i < 32; ++i)
      if (!(i & LB)) {
        const int j = i ^ MR;
        const int pi = __builtin_popcount(((unsigned)i << RS) & SM) & 1;
        const int pj = __builtin_popcount(((unsigned)j << RS) & SM) & 1;
        float a = v[i], b = v[j];
        v[i] = fmaf(pi ? -sp : sp, b, c * a);
        v[j] = fmaf(pj ? -sp : sp, a, c * b);
      }
  } else if (MR == 0) {
#pragma unroll
    for (int i = 0; i < 32; ++i) {
      float o = __shfl_xor(v[i], ML, 64);
      const int pi = __builtin_popcount(((unsigned)i << RS) & SM) & 1;
      v[i] = fmaf(pi ? -sp : sp, o, c * v[i]);
    }
  } else {
#pragma unroll
    for (int i = 0; i < 32; ++i)
      if (!(i & LB)) {
        const int j = i ^ MR;
        float oa = __shfl_xor(v[j], ML, 64);   // partner of element i
        float ob = __shfl_xor(v[i], ML, 64);   // partner of element j
        const int pi = __builtin_popcount(((unsigned)i << RS) & SM) & 1;
        const int pj = __builtin_popcount(((unsigned)j << RS) & SM) & 1;
        v[i] = fmaf(pi ? -sp : sp, oa, c * v[i]);
        v[j] = fmaf(pj ? -sp : sp, ob, c * v[j]);
      }
  }
}

// setup: input dtype flag + 66 sincos pairs (csb[0..65]=cos, csb[66..131]=sin)
__global__ void ksetup(const unsigned int* __restrict__ probe,
                       const void* __restrict__ prm,
                       float* __restrict__ csb, int* __restrict__ flagp) {
  __shared__ int anybad;
  if (threadIdx.x == 0) anybad = 0;
  __syncthreads();
  int bad = 0;
  for (int i = threadIdx.x; i < 4096; i += 256) {
    unsigned e = (probe[i] >> 7) & 0xFFu;
    bad |= (e >= 0x90u);   // |x| >= 2^17 impossible for N(0,1) bf16
  }
  if (bad) anybad = 1;
  __syncthreads();
  int f = anybad ? 0 : 1;
  if (threadIdx.x == 0) *flagp = f;
  int i = threadIdx.x;
  if (i < 66) {
    float a = f ? bf2f(((const unsigned short*)prm)[i]) : ((const float*)prm)[i];
    float sv, cv;
    sincosf(0.5f * a, &sv, &cv);
    csb[i] = cv; csb[66 + i] = sv;
  }
}

#define RC(k) csb[k], csb[66 + (k)]

// ---- sweep 1: rotations with masks in bits 0..13 ----
// tile = 2^14 consecutive elements, 512 threads, LDS 64KB f32.
// phase A: regs=l9..13, lane=l3..8, wv=l0..2 : L0 q3..13
// phase B: regs=l0..4, lane=l5..10, wv=l11..13: L0 q0..2, L1 q0..9, L2 q0..8
// phase C: = A layout:                          L1 q10..12, L2 q9..11
__global__ void __launch_bounds__(512)
ksweep1(const void* re, const void* im, float* __restrict__ Wr,
        float* __restrict__ Wi, const float* __restrict__ csb,
        const int* __restrict__ flag) {
  __shared__ float ld[16384];
  int tid = threadIdx.x;
  int f = *flag;
  int pl = blockIdx.y;
  const void* src = (pl ^ (f ? 0 : 1)) ? im : re;
  float* W = pl ? Wi : Wr;
  unsigned tb = (unsigned)blockIdx.x << 14;

  if (f) {
    const unsigned short* sp = (const unsigned short*)src + tb;
#pragma unroll
    for (int k = 0; k < 4; ++k) {
      unsigned C = (unsigned)k * 512 + tid;     // 16B chunk = 8 bf16
      uint4 q = *reinterpret_cast<const uint4*>(sp + C * 8);
      unsigned w0 = q.x, w1 = q.y, w2 = q.z, w3 = q.w;
      unsigned e0 = C * 8;
      ld[SW(e0 + 0)] = bf2f((unsigned short)(w0 & 0xFFFFu));
      ld[SW(e0 + 1)] = bf2f((unsigned short)(w0 >> 16));
      ld[SW(e0 + 2)] = bf2f((unsigned short)(w1 & 0xFFFFu));
      ld[SW(e0 + 3)] = bf2f((unsigned short)(w1 >> 16));
      ld[SW(e0 + 4)] = bf2f((unsigned short)(w2 & 0xFFFFu));
      ld[SW(e0 + 5)] = bf2f((unsigned short)(w2 >> 16));
      ld[SW(e0 + 6)] = bf2f((unsigned short)(w3 & 0xFFFFu));
      ld[SW(e0 + 7)] = bf2f((unsigned short)(w3 >> 16));
    }
  } else {
    const float* sp = (const float*)src + tb;
#pragma unroll
    for (int k = 0; k < 8; ++k) {
      unsigned C = (unsigned)k * 512 + tid;     // 16B chunk = 4 f32
      float4 t = *reinterpret_cast<const float4*>(sp + C * 4);
      unsigned e0 = C * 4;
      ld[SW(e0 + 0)] = t.x; ld[SW(e0 + 1)] = t.y;
      ld[SW(e0 + 2)] = t.z; ld[SW(e0 + 3)] = t.w;
    }
  }
  __syncthreads();

  int lane = tid & 63, wv = tid >> 6;              // wv 0..7
  unsigned lbA = (unsigned)wv | ((unsigned)lane << 3);
  unsigned pbA = tb | lbA;
  float v[32];

  // ---- phase A: L0 q3..13 ----
#pragma unroll
  for (int i = 0; i < 32; ++i) v[i] = ld[SW(lbA | ((unsigned)i << 9))];
  rot<1, 0, 9, 0x8u>(v, RC(3), pbA);
  rot<2, 0, 9, 0x10u>(v, RC(4), pbA);
  rot<4, 0, 9, 0x20u>(v, RC(5), pbA);
  rot<8, 0, 9, 0x40u>(v, RC(6), pbA);
  rot<16, 0, 9, 0x80u>(v, RC(7), pbA);
  rot<32, 0, 9, 0x100u>(v, RC(8), pbA);
  rot<0, 1, 9, 0x200u>(v, RC(9), pbA);
  rot<0, 2, 9, 0x400u>(v, RC(10), pbA);
  rot<0, 4, 9, 0x800u>(v, RC(11), pbA);
  rot<0, 8, 9, 0x1000u>(v, RC(12), pbA);
  rot<0, 16, 9, 0x2000u>(v, RC(13), pbA);
#pragma unroll
  for (int i = 0; i < 32; ++i) ld[SW(lbA | ((unsigned)i << 9))] = v[i];
  __syncthreads();

  // ---- phase B: L0 q0..2, L1 q0..9, L2 q0..8 ----
  unsigned lbB = ((unsigned)lane << 5) | ((unsigned)wv << 11);
  unsigned pbB = tb | lbB;
#pragma unroll
  for (int i = 0; i < 32; ++i) v[i] = ld[SW(lbB | (unsigned)i)];
  rot<0, 1, 0, 0x1u>(v, RC(0), pbB);
  rot<0, 2, 0, 0x2u>(v, RC(1), pbB);
  rot<0, 4, 0, 0x4u>(v, RC(2), pbB);
  rot<0, 3, 0, 0x1u>(v, RC(22), pbB);
  rot<0, 6, 0, 0x3u>(v, RC(23), pbB);
  rot<0, 12, 0, 0x7u>(v, RC(24), pbB);
  rot<0, 24, 0, 0xFu>(v, RC(25), pbB);
  rot<1, 16, 0, 0x1Fu>(v, RC(26), pbB);
  rot<3, 0, 0, 0x3Fu>(v, RC(27), pbB);
  rot<6, 0, 0, 0x7Fu>(v, RC(28), pbB);
  rot<12, 0, 0, 0xFFu>(v, RC(29), pbB);
  rot<24, 0, 0, 0x1FFu>(v, RC(30), pbB);
  rot<48, 0, 0, 0x3FFu>(v, RC(31), pbB);
  rot<0, 5, 0, 0x1u>(v, RC(44), pbB);
  rot<0, 10, 0, 0x2u>(v, RC(45), pbB);
  rot<0, 20, 0, 0x5u>(v, RC(46), pbB);
  rot<1, 8, 0, 0xAu>(v, RC(47), pbB);
  rot<2, 16, 0, 0x15u>(v, RC(48), pbB);
  rot<5, 0, 0, 0x2Au>(v, RC(49), pbB);
  rot<10, 0, 0, 0x55u>(v, RC(50), pbB);
  rot<20, 0, 0, 0xAAu>(v, RC(51), pbB);
  rot<40, 0, 0, 0x155u>(v, RC(52), pbB);
#pragma unroll
  for (int i = 0; i < 32; ++i) ld[SW(lbB | (unsigned)i)] = v[i];
  __syncthreads();

  // ---- phase C (= A layout): L1 q10..12, L2 q9..11 ----
#pragma unroll
  for (int i = 0; i < 32; ++i) v[i] = ld[SW(lbA | ((unsigned)i << 9))];
  rot<0, 6, 9, 0x7FFu>(v, RC(32), pbA);
  rot<0, 12, 9, 0xFFFu>(v, RC(33), pbA);
  rot<0, 24, 9, 0x1FFFu>(v, RC(34), pbA);
  rot<0, 5, 9, 0x2AAu>(v, RC(53), pbA);
  rot<0, 10, 9, 0x555u>(v, RC(54), pbA);
  rot<0, 20, 9, 0xAAAu>(v, RC(55), pbA);
#pragma unroll
  for (int i = 0; i < 32; ++i) ld[SW(lbA | ((unsigned)i << 9))] = v[i];
  __syncthreads();

  // store f32 (chunked contiguous)
#pragma unroll
  for (int k = 0; k < 8; ++k) {
    unsigned C = (unsigned)k * 512 + tid;
    unsigned e0 = C * 4;
    float4 t;
    t.x = ld[SW(e0 + 0)]; t.y = ld[SW(e0 + 1)];
    t.z = ld[SW(e0 + 2)]; t.w = ld[SW(e0 + 3)];
    *reinterpret_cast<float4*>(W + tb + e0) = t;
  }
}

// ---- sweep 2: rotations with masks in bits 12..21 ----
// tile = {p4..11 = blockIdx.x}: 1024 h (p12..21) x 16 lo (p0..3). 512 threads.
// compute layout: regs=p17..21, lane[4:0]=p12..16, lane5=p3, wv=p0..2.
__global__ void __launch_bounds__(512)
ksweep2(const float* __restrict__ Wr, const float* __restrict__ Wi,
        unsigned* __restrict__ tmp, const float* __restrict__ csb) {
  __shared__ float ld[16384];
  int tid = threadIdx.x;
  int lane = tid & 63, wv = tid >> 6;   // wv 0..7
  unsigned cb = blockIdx.x;             // p4..11
  unsigned lb2 = (unsigned)wv | ((((unsigned)lane >> 5) & 1u) << 3) |
                 (((unsigned)lane & 31u) << 4);
  unsigned pb2 = (unsigned)wv | ((((unsigned)lane >> 5) & 1u) << 3) |
                 (cb << 4) | (((unsigned)lane & 31u) << 12);
  unsigned hr[16];
#pragma unroll
  for (int k = 0; k < 16; ++k) hr[k] = 0;

  for (int pl = 0; pl < 2; ++pl) {
    if (pl) __syncthreads();
    const float* W = pl ? Wi : Wr;
#pragma unroll
    for (int k = 0; k < 8; ++k) {
      unsigned C = (unsigned)k * 512 + tid;
      unsigned h = C >> 2, loq = C & 3;
      float4 t = *reinterpret_cast<const float4*>(
          W + ((size_t)h << 12) + ((size_t)cb << 4) + loq * 4);
      unsigned e0 = C * 4;   // local l = (h<<4) + loq*4
      ld[SW(e0 + 0)] = t.x; ld[SW(e0 + 1)] = t.y;
      ld[SW(e0 + 2)] = t.z; ld[SW(e0 + 3)] = t.w;
    }
    __syncthreads();
    float v[32];
#pragma unroll
    for (int i = 0; i < 32; ++i) v[i] = ld[SW(lb2 | ((unsigned)i << 9))];
    // L0 q14..21
    rot<4, 0, 17, (1u << 14)>(v, RC(14), pb2);
    rot<8, 0, 17, (1u << 15)>(v, RC(15), pb2);
    rot<16, 0, 17, (1u << 16)>(v, RC(16), pb2);
    rot<0, 1, 17, (1u << 17)>(v, RC(17), pb2);
    rot<0, 2, 17, (1u << 18)>(v, RC(18), pb2);
    rot<0, 4, 17, (1u << 19)>(v, RC(19), pb2);
    rot<0, 8, 17, (1u << 20)>(v, RC(20), pb2);
    rot<0, 16, 17, (1u << 21)>(v, RC(21), pb2);
    // L1 q13..21 (mask {q,q+1}; sign parity p0..q)
    rot<6, 0, 17, 0x3FFFu>(v, RC(35), pb2);
    rot<12, 0, 17, 0x7FFFu>(v, RC(36), pb2);
    rot<24, 0, 17, 0xFFFFu>(v, RC(37), pb2);
    rot<16, 1, 17, 0x1FFFFu>(v, RC(38), pb2);
    rot<0, 3, 17, 0x3FFFFu>(v, RC(39), pb2);
    rot<0, 6, 17, 0x7FFFFu>(v, RC(40), pb2);
    rot<0, 12, 17, 0xFFFFFu>(v, RC(41), pb2);
    rot<0, 24, 17, 0x1FFFFFu>(v, RC(42), pb2);
    rot<0, 16, 17, 0x3FFFFFu>(v, RC(43), pb2);
    // L2 q12..21 (mask {q,q+2}; sign parity {q,q-2,...})
    rot<5, 0, 17, 0x1555u>(v, RC(56), pb2);
    rot<10, 0, 17, 0x2AAAu>(v, RC(57), pb2);
    rot<20, 0, 17, 0x5555u>(v, RC(58), pb2);
    rot<8, 1, 17, 0xAAAAu>(v, RC(59), pb2);
    rot<16, 2, 17, 0x15555u>(v, RC(60), pb2);
    rot<0, 5, 17, 0x2AAAAu>(v, RC(61), pb2);
    rot<0, 10, 17, 0x55555u>(v, RC(62), pb2);
    rot<0, 20, 17, 0xAAAAAu>(v, RC(63), pb2);
    rot<0, 8, 17, 0x155555u>(v, RC(64), pb2);
    rot<0, 16, 17, 0x2AAAAAu>(v, RC(65), pb2);
#pragma unroll
    for (int i = 0; i < 32; ++i) ld[SW(lb2 | ((unsigned)i << 9))] = v[i];
    __syncthreads();
    if (pl == 0) {
#pragma unroll
      for (int k = 0; k < 8; ++k) {
        unsigned C = (unsigned)k * 512 + tid;
        unsigned e0 = C * 4;
#pragma unroll
        for (int j = 0; j < 4; ++j) {
          int i = k * 4 + j;
          unsigned b = f2bf(ld[SW(e0 + j)]);
          hr[i >> 1] |= b << ((i & 1) * 16);
        }
      }
    } else {
#pragma unroll
      for (int k = 0; k < 8; ++k) {
        unsigned C = (unsigned)k * 512 + tid;
        unsigned h = C >> 2, loq = C & 3;
        unsigned e0 = C * 4;
        uint4 o;
        {
          int i = k * 4;
          unsigned r0 = (hr[(i + 0) >> 1] >> (((i + 0) & 1) * 16)) & 0xFFFFu;
          unsigned r1 = (hr[(i + 1) >> 1] >> (((i + 1) & 1) * 16)) & 0xFFFFu;
          unsigned r2 = (hr[(i + 2) >> 1] >> (((i + 2) & 1) * 16)) & 0xFFFFu;
          unsigned r3 = (hr[(i + 3) >> 1] >> (((i + 3) & 1) * 16)) & 0xFFFFu;
          o.x = r0 | ((unsigned)f2bf(ld[SW(e0 + 0)]) << 16);
          o.y = r1 | ((unsigned)f2bf(ld[SW(e0 + 1)]) << 16);
          o.z = r2 | ((unsigned)f2bf(ld[SW(e0 + 2)]) << 16);
          o.w = r3 | ((unsigned)f2bf(ld[SW(e0 + 3)]) << 16);
        }
        *reinterpret_cast<uint4*>(tmp + (((size_t)h << 12) |
                                         ((size_t)cb << 4) | (loq * 4))) = o;
      }
    }
  }
}

// ---- final gather: out[l] = tmp[sigma^2(l)] ----
// sigma^2(l^e) = sigma^2(l) ^ {0,5,10,15}[e]; base 4-aligned -> all 4 targets
// in one aligned 16-u32 (64B) window.
__global__ void __launch_bounds__(256)
kfinal(const unsigned* __restrict__ tmp, unsigned* __restrict__ out32) {
  unsigned T = blockIdx.x * 256 + threadIdx.x;   // quad id [0, 2^20)
  unsigned lb = T << 2;
  unsigned s = (lb ^ (lb << 2)) & IDXMASK;       // %4 == 0
  const uint4* w = reinterpret_cast<const uint4*>(tmp + (s & ~15u));
  uint4 a = w[0], b = w[1], c = w[2], d = w[3];
  uint4 o;
  switch ((s >> 2) & 3u) {
    case 0: o = make_uint4(a.x, b.y, c.z, d.w); break;   // 0,5,10,15
    case 1: o = make_uint4(b.x, a.y, d.z, c.w); break;   // 4,1,14,11
    case 2: o = make_uint4(c.x, d.y, a.z, b.w); break;   // 8,13,2,7
    default: o = make_uint4(d.x, c.y, b.z, a.w); break;  // 12,9,6,3
  }
  *reinterpret_cast<uint4*>(out32 + lb) = o;
}

// ---------------- proven tier-C fallback (R6) ----------------
__global__ void __launch_bounds__(256)
kinit(const void* s0, const void* s1, float* d0, float* d1,
      const int* __restrict__ flag, int basepl) {
  int pl = blockIdx.y + basepl;
  int f = *flag;
  const void* src = (pl ^ (f ? 0 : 1)) ? s1 : s0;
  float* dst = pl ? d1 : d0;
  unsigned p = blockIdx.x * 256 + threadIdx.x;
  unsigned q = (p ^ (p << 2)) & IDXMASK;
  dst[p] = f ? bf2f(((const unsigned short*)src)[q]) : ((const float*)src)[q];
}
__global__ void __launch_bounds__(256)
kpass(float* b0, float* b1, const float* __restrict__ csb,
      int L, int qa, unsigned ma, unsigned mb) {
  int k = L * 22 + qa;
  float ca = csb[k], sa = csb[66 + k];
  float cb = csb[k + 1], sb = csb[66 + k + 1];
  float* buf = blockIdx.y ? b1 : b0;
  unsigned t = blockIdx.x * 256 + threadIdx.x;
  unsigned j = (t & ((1u << qa) - 1u)) | ((t >> qa) << (qa + 2));
  unsigned p = j;
  if (L == 0)      { p ^= p << 2; p ^= p << 4; p ^= p << 8; p ^= p << 16; }
  else if (L == 1) { p ^= p << 1; p ^= p << 2; p ^= p << 4; p ^= p << 8; p ^= p << 16; }
  p &= IDXMASK;
  unsigned mc = ma ^ mb;
  float x0 = buf[p], x1 = buf[p ^ ma], x2 = buf[p ^ mb], x3 = buf[p ^ mc];
  float y0 = ca * x0 - sa * x1, y1 = sa * x0 + ca * x1;
  float y2 = ca * x2 - sa * x3, y3 = sa * x2 + ca * x3;
  buf[p]      = cb * y0 - sb * y2;
  buf[p ^ ma] = cb * y1 - sb * y3;
  buf[p ^ mb] = sb * y0 + cb * y2;
  buf[p ^ mc] = sb * y1 + cb * y3;
}
__global__ void __launch_bounds__(256)
kpark(const float* __restrict__ fv, unsigned short* __restrict__ park) {
  unsigned j = blockIdx.x * 256 + threadIdx.x;
  park[j] = f2bf(fv[j]);
}
__global__ void __launch_bounds__(256)
kmerge(const unsigned short* __restrict__ park, unsigned int* outw) {
  unsigned j = blockIdx.x * 256 + threadIdx.x;
  float vv = __uint_as_float(outw[j]);
  outw[j] = (unsigned)park[j] | ((unsigned)f2bf(vv) << 16);
}
static inline unsigned pmask(int q, int L) {
  unsigned r = 0;
  if (L == 0)      for (unsigned m = 1u << q; m < NSTATES; m <<= 2) r ^= m;
  else if (L == 1) for (unsigned m = 1u << q; m < NSTATES; m <<= 1) r ^= m;
  else r = 1u << q;
  return r;
}

extern "C" void kernel_launch(void* const* d_in, const int* in_sizes, int n_in,
                              void* d_out, int out_size, void* d_ws, size_t ws_size,
                              hipStream_t stream) {
  (void)out_size;
  const void* prm = d_in[0];
  const void* re  = d_in[1];
  const void* im  = d_in[2];
  if (in_sizes[0] != 66) {   // defensive size-based remap
    const void* big[2] = {nullptr, nullptr};
    int nb = 0;
    for (int i = 0; i < n_in; ++i) {
      if (in_sizes[i] == 66) prm = d_in[i];
      else if (nb < 2) big[nb++] = d_in[i];
    }
    if (nb == 2) { re = big[0]; im = big[1]; }
  }
  const size_t N = NSTATES;

  if (ws_size >= N * 12 + 1024) {
    // ---- fast path: forward-frame 2-sweep + gather ----
    float* Wr = (float*)d_ws;
    float* Wi = Wr + N;
    unsigned* tmp = (unsigned*)(Wi + N);
    float* csb = (float*)(tmp + N);
    int* flag = (int*)(csb + 140);
    ksetup<<<1, 256, 0, stream>>>((const unsigned int*)re, prm, csb, flag);
    ksweep1<<<dim3(256, 2), 512, 0, stream>>>(re, im, Wr, Wi, csb, flag);
    ksweep2<<<dim3(256), 512, 0, stream>>>(Wr, Wi, tmp, csb);
    kfinal<<<dim3(4096), 256, 0, stream>>>(tmp, (unsigned*)d_out);
  } else {
    // ---- tier C (proven R6): d_out as f32 buffer; ~8.4MB ws ----
    float* F = (float*)d_out;
    unsigned short* park = (unsigned short*)d_ws;
    float* csb = (float*)((char*)d_ws + N * 2);
    int* flag = (int*)(csb + 140);
    dim3 blk(256);
    ksetup<<<1, 256, 0, stream>>>((const unsigned int*)re, prm, csb, flag);
    kinit<<<dim3(16384, 1), blk, 0, stream>>>(re, im, F, F, flag, 0);
    for (int L = 0; L < 3; ++L)
      for (int qa = 0; qa < 22; qa += 2)
        kpass<<<dim3(4096, 1), blk, 0, stream>>>(F, F, csb, L, qa,
                                                 pmask(qa, L), pmask(qa + 1, L));
    kpark<<<dim3(16384), blk, 0, stream>>>(F, park);
    kinit<<<dim3(16384, 1), blk, 0, stream>>>(re, im, F, F, flag, 1);
    for (int L = 0; L < 3; ++L)
      for (int qa = 0; qa < 22; qa += 2)
        kpass<<<dim3(4096, 1), blk, 0, stream>>>(F, F, csb, L, qa,
                                                 pmask(qa, L), pmask(qa + 1, L));
    kmerge<<<dim3(16384), blk, 0, stream>>>(park, (unsigned int*)d_out);
  }
}